// Round 10
// baseline (6312.317 us; speedup 1.0000x reference)
//
#include <hip/hip_runtime.h>
#include <hip/hip_bf16.h>

typedef __hip_bfloat16 bf16;
typedef __attribute__((ext_vector_type(8))) short short8;
typedef __attribute__((ext_vector_type(4))) float float4v;

#define B_    1024
#define H_    512
#define G4H   2048
#define F_    32
#define CIN_  4
#define K_    30
#define STRIDE_ 6
#define L_    924
#define T_    150
#define KD_   40
#define NSTEPS_ 10
#define BH    (B_ * H_)

__device__ __forceinline__ float sigmoidf_(float x) { return 1.f / (1.f + __expf(-x)); }
__device__ __forceinline__ float tanhf_(float x)    { return 1.f - 2.f / (__expf(2.f * x) + 1.f); }
__device__ __forceinline__ float b2f_(short s) {
    return __uint_as_float(((unsigned)(unsigned short)s) << 16);
}
// write-through (agent-scope) bf16 store: data lands at the coherent point
__device__ __forceinline__ void stwt_(bf16* p, float v) {
    union { __hip_bfloat16 b; unsigned short u; } cv;
    cv.b = __float2bfloat16(v);
    __hip_atomic_store((unsigned short*)p, cv.u, __ATOMIC_RELAXED, __HIP_MEMORY_SCOPE_AGENT);
}
// agent-scope 16B load as two 8B relaxed atomics: force-miss to coherent point,
// no cache-maintenance (buffer_inv) needed for cross-block data.
__device__ __forceinline__ short8 lda16_(const bf16* p) {
    const long long* q = (const long long*)p;
    long long a = __hip_atomic_load(q,     __ATOMIC_RELAXED, __HIP_MEMORY_SCOPE_AGENT);
    long long b = __hip_atomic_load(q + 1, __ATOMIC_RELAXED, __HIP_MEMORY_SCOPE_AGENT);
    union { long long ll[2]; short8 s; } u; u.ll[0] = a; u.ll[1] = b;
    return u.s;
}

// ---------------------------------------------------------------------------
__global__ __launch_bounds__(256) void cvt_kernel(const float* __restrict__ src,
                                                  bf16* __restrict__ dst, int n) {
    int i = blockIdx.x * 256 + threadIdx.x;
    if (i < n) dst[i] = __float2bfloat16(src[i]);
}

__global__ void bias_kernel(const float* __restrict__ bih0, const float* __restrict__ bhh0,
                            const float* __restrict__ bih1, const float* __restrict__ bhh1,
                            float* __restrict__ b0, float* __restrict__ b1) {
    int i = blockIdx.x * 256 + threadIdx.x;
    if (i < G4H)      b0[i] = bih0[i] + bhh0[i];
    else if (i < 2*G4H) { int j = i - G4H; b1[j] = bih1[j] + bhh1[j]; }
}

// ---------------------------------------------------------------------------
__global__ __launch_bounds__(256) void conv_kernel(
    const float* __restrict__ x, const float* __restrict__ w,
    const float* __restrict__ cb, bf16* __restrict__ seq)
{
    __shared__ float w_lds[CIN_ * K_ * F_];
    __shared__ float x_lds[CIN_ * L_];
    int tid = threadIdx.x;
    int b = blockIdx.x;
    for (int i = tid; i < CIN_ * K_ * F_; i += 256) {
        int f = i & 31, r = i >> 5;
        w_lds[r * 32 + f] = w[f * (CIN_ * K_) + r];
    }
    const float* xb = x + (size_t)b * (CIN_ * L_);
    for (int i = tid; i < CIN_ * L_; i += 256)
        x_lds[i] = xb[i];
    __syncthreads();
    int f = tid & 31, tt = tid >> 5;
    float cbf = cb[f];
    for (int t0 = 0; t0 < T_; t0 += 8) {
        int t = t0 + tt;
        if (t < T_) {
            float acc = cbf;
            #pragma unroll
            for (int c = 0; c < CIN_; ++c) {
                const float* xr = x_lds + c * L_ + t * STRIDE_;
                const float* wr = w_lds + c * K_ * 32 + f;
                #pragma unroll
                for (int k = 0; k < K_; ++k)
                    acc += xr[k] * wr[k * 32];
            }
            acc = fmaxf(acc, 0.f);
            seq[(size_t)t * (B_ * F_) + b * F_ + f] = __float2bfloat16(acc);
        }
    }
}

// ---------------------------------------------------------------------------
// sync: packed per-group flags (32 ints = 128B). Producers release-store their
// own int. Consumers: combined poll of up to two groups (lanes 0-15 group A,
// lanes 16-31 group B), 8B atomic loads, gentle backoff. NO acquire fence —
// consumers read produced data with agent-scope atomic loads instead.
// ---------------------------------------------------------------------------
__device__ __forceinline__ void waitg(const int* fa, int ta, const int* fb, int tb) {
    const int t = threadIdx.x;
    if (t < 32) {
        const long long* p = nullptr; int tgt = 0;
        if (t < 16) { if (fa && ta > 0) { p = (const long long*)fa + t;        tgt = ta; } }
        else        { if (fb && tb > 0) { p = (const long long*)fb + (t - 16); tgt = tb; } }
        if (__any(p != nullptr)) {
            for (int n = 0; ; ++n) {
                long long v = p ? __hip_atomic_load(p, __ATOMIC_RELAXED, __HIP_MEMORY_SCOPE_AGENT)
                                : 0;
                bool ok = (p == nullptr) || ((int)v >= tgt && (int)(v >> 32) >= tgt);
                if (__all(ok)) break;
                if (n < 4) __builtin_amdgcn_s_sleep(1);
                else       __builtin_amdgcn_s_sleep(8);
            }
        }
    }
    __syncthreads();
}

__device__ __forceinline__ void signal1(int* f, int val) {
    __syncthreads();                       // compiler drains vmcnt(0) per wave here
    if (threadIdx.x == 0) {
        __builtin_amdgcn_s_waitcnt(0);
        __hip_atomic_store(f, val, __ATOMIC_RELAXED, __HIP_MEMORY_SCOPE_AGENT);
    }
}

// ---------------------------------------------------------------------------
// GEMM accumulate: acc += X[m-rows] @ W^T (W fragment-major in LDS).
// ATOM: read X with agent-scope atomic loads (cross-block-produced data).
// ---------------------------------------------------------------------------
#define MFMA_ __builtin_amdgcn_mfma_f32_16x16x32_bf16
template<int NKS, int XSTR, bool ATOM>
__device__ __forceinline__ void gemm_acc(
    const bf16* __restrict__ X, const short8* __restrict__ W,
    float4v (&acc)[4][4], int mrow, int quad, int lane)
{
    for (int ks = 0; ks < NKS; ++ks) {
        short8 av[4];
        #pragma unroll
        for (int ms = 0; ms < 4; ++ms) {
            const bf16* p = X + (size_t)(mrow + ms * 16) * XSTR + ks * 32 + quad * 8;
            av[ms] = ATOM ? lda16_(p) : *(const short8*)p;
        }
        #pragma unroll
        for (int g = 0; g < 4; ++g) {
            short8 bfr = W[(ks * 4 + g) * 64 + lane];
            #pragma unroll
            for (int ms = 0; ms < 4; ++ms)
                acc[ms][g] = MFMA_(av[ms], bfr, acc[ms][g], 0, 0, 0);
        }
    }
}

__device__ __forceinline__ void epilogue_(
    float4v (&acc)[4][4], float (&creg)[16], const float* __restrict__ bias,
    bf16* __restrict__ Hout, int m0, int j0, int wid, int lane)
{
    const int row16 = lane & 15;
    const int quad  = lane >> 4;
    const int j = j0 + row16;
    const float bi  = bias[j];
    const float bff = bias[H_ + j];
    const float bg  = bias[2 * H_ + j];
    const float bo  = bias[3 * H_ + j];
    #pragma unroll
    for (int ms = 0; ms < 4; ++ms) {
        #pragma unroll
        for (int r = 0; r < 4; ++r) {
            int brow = m0 + wid * 64 + ms * 16 + quad * 4 + r;
            float ig = sigmoidf_(acc[ms][0][r] + bi);
            float fg = sigmoidf_(acc[ms][1][r] + bff);
            float gg = tanhf_(acc[ms][2][r] + bg);
            float og = sigmoidf_(acc[ms][3][r] + bo);
            float cn = fg * creg[ms * 4 + r] + ig * gg;
            creg[ms * 4 + r] = cn;
            stwt_(Hout + (size_t)brow * H_ + j, og * tanhf_(cn));
        }
    }
}

// ---------------------------------------------------------------------------
struct PP {
    const bf16 *seq, *Wih0, *Whh0, *Wih1, *Whh1, *dwb;
    const float *b0, *b1, *dec_b;
    float *fut;
    bf16 *h0, *h1, *y;       // h0/h1: 3 slots of [B,H] each
    int *flags;              // f0[4][32], f1[4][32], fy[4][32] packed ints
};

// Persistent kernel, 256 blocks (1/CU). Swizzle bid = jj*8 + layer*4 + mg.
// flag = t+1 after step t. 3 h-slots (slot = t%3). Waits:
//   L0(t): seq-gemm first (no dep); then f0>=t (peers h0[t-1]) & f1>=t-2 (slot)
//   L1(t): f1>=t (peers h1[t-1] + slot) -> h1prev-gemm; f0>=t+1 -> h0-gemm
__global__ __launch_bounds__(256, 1) void lstm_persist(PP P) {
    __shared__ short8 WldsH[4096];   // Whh slice, 64 KB
    __shared__ short8 WldsI[4096];   // Wih slice, 64 KB (L0 uses 256 entries)

    const int bid   = blockIdx.x;
    const int gsw   = bid & 7;
    const bool isL0 = (gsw < 4);
    const int mg    = gsw & 3;
    const int jj    = bid >> 3;
    const int lb    = mg * 32 + jj;
    const int j0    = jj * 16;
    const int m0    = mg * 256;
    const int tid   = threadIdx.x;
    const int wid   = tid >> 6;
    const int lane  = tid & 63;
    const int quad  = lane >> 4;
    const int mrow  = m0 + wid * 64 + (lane & 15);

    // stage weight slices into LDS (frag-major); pre-kernel data, normal loads
    {
        const bf16* Whh = isL0 ? P.Whh0 : P.Whh1;
        for (int i = 0; i < 16; ++i) {
            int s = tid + i * 256;
            int frag = s >> 6, ln = s & 63;
            int ks = frag >> 2, g = frag & 3;
            WldsH[s] = *(const short8*)(Whh + (size_t)(g * H_ + j0 + (ln & 15)) * H_
                                        + ks * 32 + (ln >> 4) * 8);
        }
        if (isL0) {
            if (tid < 256) {
                int frag = tid >> 6, ln = tid & 63;
                int g = frag & 3;   // ks = 0
                WldsI[tid] = *(const short8*)(P.Wih0 + (size_t)(g * H_ + j0 + (ln & 15)) * F_
                                              + (ln >> 4) * 8);
            }
        } else {
            for (int i = 0; i < 16; ++i) {
                int s = tid + i * 256;
                int frag = s >> 6, ln = s & 63;
                int ks = frag >> 2, g = frag & 3;
                WldsI[s] = *(const short8*)(P.Wih1 + (size_t)(g * H_ + j0 + (ln & 15)) * H_
                                            + ks * 32 + (ln >> 4) * 8);
            }
        }
        __syncthreads();
    }

    float creg[16];
    #pragma unroll
    for (int i = 0; i < 16; ++i) creg[i] = 0.f;

    int* f0 = P.flags;              // [4][32]
    int* f1 = P.flags + 128;
    int* fy = P.flags + 256;
    const int* f0g = f0 + mg * 32;
    const int* f1g = f1 + mg * 32;
    const int* fyg = fy + mg * 32;

    float4v acc[4][4];

    if (isL0) {
        // encoder t = 0..149
        for (int t = 0; t < T_; ++t) {
            #pragma unroll
            for (int ms = 0; ms < 4; ++ms)
                #pragma unroll
                for (int g = 0; g < 4; ++g) acc[ms][g] = (float4v){0.f,0.f,0.f,0.f};
            gemm_acc<1, 32, false>(P.seq + (size_t)t * B_ * F_, WldsI, acc, mrow, quad, lane);
            waitg(f0g, t, f1g, t - 2);                 // peers h0[t-1]; slot safety
            gemm_acc<16, 512, true>(P.h0 + (size_t)((t + 2) % 3) * BH, WldsH, acc, mrow, quad, lane);
            epilogue_(acc, creg, P.b0, P.h0 + (size_t)(t % 3) * BH, m0, j0, wid, lane);
            signal1(f0 + lb, t + 1);
        }
        // decoder
        for (int s = 0; s <= NSTEPS_; ++s) {
            waitg(f1g, T_ + s, nullptr, 0);            // h1[T-1+s] ready
            float yacc;
            int id = lb * 256 + tid;                   // b*32 + f
            {
                int br = id >> 5, f = id & 31;
                const bf16* hv = P.h1 + (size_t)((T_ - 1 + s) % 3) * BH + (size_t)br * H_;
                const short8* wv = (const short8*)(P.dwb + (size_t)f * H_);
                yacc = P.dec_b[f];
                for (int i = 0; i < H_ / 8; ++i) {
                    short8 h8 = lda16_(hv + i * 8), w8 = wv[i];
                    #pragma unroll
                    for (int k = 0; k < 8; ++k)
                        yacc += b2f_(h8[k]) * b2f_(w8[k]);
                }
            }
            if (s >= 1) waitg(f0g, T_ + s, nullptr, 0); // peers consumed previous y
            stwt_(P.y + id, yacc);
            if (s >= 1) {
                int br = id >> 5, f = id & 31;
                P.fut[(size_t)br * (F_ * NSTEPS_) + f * NSTEPS_ + (s - 1)] = yacc;
            }
            signal1(fy + lb, s + 1);
            if (s < NSTEPS_) {
                int t = T_ + s;
                waitg(fyg, s + 1, nullptr, 0);         // y ready (cross-block)
                #pragma unroll
                for (int ms = 0; ms < 4; ++ms)
                    #pragma unroll
                    for (int g = 0; g < 4; ++g) acc[ms][g] = (float4v){0.f,0.f,0.f,0.f};
                gemm_acc<1, 32, true>(P.y, WldsI, acc, mrow, quad, lane);
                waitg(f0g, t, f1g, t - 2);
                gemm_acc<16, 512, true>(P.h0 + (size_t)((t + 2) % 3) * BH, WldsH, acc, mrow, quad, lane);
                epilogue_(acc, creg, P.b0, P.h0 + (size_t)(t % 3) * BH, m0, j0, wid, lane);
                signal1(f0 + lb, t + 1);
            }
        }
    } else {
        // layer 1: t = 0..159
        for (int t = 0; t < T_ + NSTEPS_; ++t) {
            waitg(f1g, t, nullptr, 0);                 // peers h1[t-1] + slot safety
            #pragma unroll
            for (int ms = 0; ms < 4; ++ms)
                #pragma unroll
                for (int g = 0; g < 4; ++g) acc[ms][g] = (float4v){0.f,0.f,0.f,0.f};
            gemm_acc<16, 512, true>(P.h1 + (size_t)((t + 2) % 3) * BH, WldsH, acc, mrow, quad, lane);
            waitg(f0g, t + 1, nullptr, 0);             // h0[t] ready
            gemm_acc<16, 512, true>(P.h0 + (size_t)(t % 3) * BH, WldsI, acc, mrow, quad, lane);
            epilogue_(acc, creg, P.b1, P.h1 + (size_t)(t % 3) * BH, m0, j0, wid, lane);
            signal1(f1 + lb, t + 1);
        }
    }
}

// ---------------------------------------------------------------------------
__global__ __launch_bounds__(256) void deconv_kernel(
    const float* __restrict__ fut, const float* __restrict__ dw,
    float* __restrict__ out)
{
    int idx = blockIdx.x * 256 + threadIdx.x;
    if (idx >= B_ * 49) return;
    int b = idx / 49, jj = idx % 49;
    int tlo = jj - (KD_ - 1); if (tlo < 0) tlo = 0;
    int thi = jj; if (thi > NSTEPS_ - 1) thi = NSTEPS_ - 1;
    float acc = 0.f;
    for (int f = 0; f < F_; ++f) {
        const float* fr = fut + (size_t)b * (F_ * NSTEPS_) + f * NSTEPS_;
        const float* wr = dw + f * KD_;
        for (int t = tlo; t <= thi; ++t)
            acc += fr[t] * wr[jj - t];
    }
    out[idx] = acc;
}

// ---------------------------------------------------------------------------
extern "C" void kernel_launch(void* const* d_in, const int* in_sizes, int n_in,
                              void* d_out, int out_size, void* d_ws, size_t ws_size,
                              hipStream_t stream) {
    const float* x       = (const float*)d_in[0];
    const float* conv_w  = (const float*)d_in[1];
    const float* conv_b  = (const float*)d_in[2];
    const float* Wih0f   = (const float*)d_in[3];
    const float* Whh0f   = (const float*)d_in[4];
    const float* bih0    = (const float*)d_in[5];
    const float* bhh0    = (const float*)d_in[6];
    const float* Wih1f   = (const float*)d_in[7];
    const float* Whh1f   = (const float*)d_in[8];
    const float* bih1    = (const float*)d_in[9];
    const float* bhh1    = (const float*)d_in[10];
    const float* dec_wf  = (const float*)d_in[11];
    const float* dec_b   = (const float*)d_in[12];
    const float* deconvw = (const float*)d_in[13];
    float* out = (float*)d_out;

    char* ws = (char*)d_ws;
    size_t off = 0;
    auto alloc = [&](size_t bytes) { char* p = ws + off; off = (off + bytes + 255) & ~(size_t)255; return p; };
    bf16*  seq   = (bf16*) alloc((size_t)T_ * B_ * F_ * 2);
    float* b0v   = (float*)alloc(G4H * 4);
    float* b1v   = (float*)alloc(G4H * 4);
    bf16*  h0    = (bf16*) alloc((size_t)3 * BH * 2);
    bf16*  h1    = (bf16*) alloc((size_t)3 * BH * 2);
    bf16*  y     = (bf16*) alloc((size_t)B_ * F_ * 2);
    float* fut   = (float*)alloc((size_t)B_ * F_ * NSTEPS_ * 4);
    bf16*  Wih0b = (bf16*) alloc((size_t)G4H * F_ * 2);
    bf16*  Whh0b = (bf16*) alloc((size_t)G4H * H_ * 2);
    bf16*  Wih1b = (bf16*) alloc((size_t)G4H * H_ * 2);
    bf16*  Whh1b = (bf16*) alloc((size_t)G4H * H_ * 2);
    bf16*  dec_wb= (bf16*) alloc((size_t)F_ * H_ * 2);
    int*   flags = (int*)  alloc(384 * 4);

    hipMemsetAsync(h0, 0, (size_t)3 * BH * 2, stream);
    hipMemsetAsync(h1, 0, (size_t)3 * BH * 2, stream);
    hipMemsetAsync(flags, 0, 384 * 4, stream);

    cvt_kernel<<<(G4H * F_ + 255) / 256, 256, 0, stream>>>(Wih0f, Wih0b, G4H * F_);
    cvt_kernel<<<(G4H * H_ + 255) / 256, 256, 0, stream>>>(Whh0f, Whh0b, G4H * H_);
    cvt_kernel<<<(G4H * H_ + 255) / 256, 256, 0, stream>>>(Wih1f, Wih1b, G4H * H_);
    cvt_kernel<<<(G4H * H_ + 255) / 256, 256, 0, stream>>>(Whh1f, Whh1b, G4H * H_);
    cvt_kernel<<<(F_ * H_ + 255) / 256, 256, 0, stream>>>(dec_wf, dec_wb, F_ * H_);

    bias_kernel<<<16, 256, 0, stream>>>(bih0, bhh0, bih1, bhh1, b0v, b1v);
    conv_kernel<<<B_, 256, 0, stream>>>(x, conv_w, conv_b, seq);

    PP P;
    P.seq = seq; P.Wih0 = Wih0b; P.Whh0 = Whh0b; P.Wih1 = Wih1b; P.Whh1 = Whh1b;
    P.dwb = dec_wb; P.b0 = b0v; P.b1 = b1v; P.dec_b = dec_b;
    P.fut = fut; P.h0 = h0; P.h1 = h1; P.y = y;
    P.flags = flags;

    void* args[] = { &P };
    hipError_t err = hipLaunchCooperativeKernel((const void*)lstm_persist,
                                                dim3(256), dim3(256), args, 0, stream);
    if (err != hipSuccess) {
        lstm_persist<<<256, 256, 0, stream>>>(P);
    }

    deconv_kernel<<<196, 256, 0, stream>>>(fut, deconvw, out);
}

// Round 11
// 5396.790 us; speedup vs baseline: 1.1696x; 1.1696x over previous
//
#include <hip/hip_runtime.h>
#include <hip/hip_bf16.h>

typedef __hip_bfloat16 bf16;
typedef __attribute__((ext_vector_type(8))) short short8;
typedef __attribute__((ext_vector_type(4))) float float4v;

#define B_    1024
#define H_    512
#define G4H   2048
#define F_    32
#define CIN_  4
#define K_    30
#define STRIDE_ 6
#define L_    924
#define T_    150
#define KD_   40
#define NSTEPS_ 10
#define BH    (B_ * H_)

__device__ __forceinline__ float sigmoidf_(float x) { return 1.f / (1.f + __expf(-x)); }
__device__ __forceinline__ float tanhf_(float x)    { return 1.f - 2.f / (__expf(2.f * x) + 1.f); }
__device__ __forceinline__ float b2f_(short s) {
    return __uint_as_float(((unsigned)(unsigned short)s) << 16);
}

// ---------------------------------------------------------------------------
__global__ __launch_bounds__(256) void cvt_kernel(const float* __restrict__ src,
                                                  bf16* __restrict__ dst, int n) {
    int i = blockIdx.x * 256 + threadIdx.x;
    if (i < n) dst[i] = __float2bfloat16(src[i]);
}

__global__ void bias_kernel(const float* __restrict__ bih0, const float* __restrict__ bhh0,
                            const float* __restrict__ bih1, const float* __restrict__ bhh1,
                            float* __restrict__ b0, float* __restrict__ b1) {
    int i = blockIdx.x * 256 + threadIdx.x;
    if (i < G4H)      b0[i] = bih0[i] + bhh0[i];
    else if (i < 2*G4H) { int j = i - G4H; b1[j] = bih1[j] + bhh1[j]; }
}

// ---------------------------------------------------------------------------
__global__ __launch_bounds__(256) void conv_kernel(
    const float* __restrict__ x, const float* __restrict__ w,
    const float* __restrict__ cb, bf16* __restrict__ seq)
{
    __shared__ float w_lds[CIN_ * K_ * F_];
    __shared__ float x_lds[CIN_ * L_];
    int tid = threadIdx.x;
    int b = blockIdx.x;
    for (int i = tid; i < CIN_ * K_ * F_; i += 256) {
        int f = i & 31, r = i >> 5;
        w_lds[r * 32 + f] = w[f * (CIN_ * K_) + r];
    }
    const float* xb = x + (size_t)b * (CIN_ * L_);
    for (int i = tid; i < CIN_ * L_; i += 256)
        x_lds[i] = xb[i];
    __syncthreads();
    int f = tid & 31, tt = tid >> 5;
    float cbf = cb[f];
    for (int t0 = 0; t0 < T_; t0 += 8) {
        int t = t0 + tt;
        if (t < T_) {
            float acc = cbf;
            #pragma unroll
            for (int c = 0; c < CIN_; ++c) {
                const float* xr = x_lds + c * L_ + t * STRIDE_;
                const float* wr = w_lds + c * K_ * 32 + f;
                #pragma unroll
                for (int k = 0; k < K_; ++k)
                    acc += xr[k] * wr[k * 32];
            }
            acc = fmaxf(acc, 0.f);
            seq[(size_t)t * (B_ * F_) + b * F_ + f] = __float2bfloat16(acc);
        }
    }
}

// ---------------------------------------------------------------------------
// GEMM accumulate: acc += X[m-rows] @ W^T (W fragment-major in LDS).
// Compile-time bounds only (r2 lesson: runtime bounds -> scratch spill).
// ---------------------------------------------------------------------------
#define MFMA_ __builtin_amdgcn_mfma_f32_16x16x32_bf16
template<int NKS, int XSTR>
__device__ __forceinline__ void gemm_acc(
    const bf16* __restrict__ X, const short8* __restrict__ W,
    float4v (&acc)[4][4], int mrow, int quad, int lane)
{
    for (int ks = 0; ks < NKS; ++ks) {
        short8 av[4];
        #pragma unroll
        for (int ms = 0; ms < 4; ++ms)
            av[ms] = *(const short8*)(X + (size_t)(mrow + ms * 16) * XSTR
                                      + ks * 32 + quad * 8);
        #pragma unroll
        for (int g = 0; g < 4; ++g) {
            short8 bfr = W[(ks * 4 + g) * 64 + lane];
            #pragma unroll
            for (int ms = 0; ms < 4; ++ms)
                acc[ms][g] = MFMA_(av[ms], bfr, acc[ms][g], 0, 0, 0);
        }
    }
}

// ---------------------------------------------------------------------------
struct LA {
    const bf16* X;      // [1024 x Kx] (null => slot inactive)
    const bf16* Wih;    // [2048 x Kx]
    const bf16* Whh;    // [2048 x 512]
    const bf16* Hin;    // [1024 x 512]
    const float* bias;  // [2048]
    float* C;           // [1024 x 512] fp32, in/out
    bf16* Hout;         // [1024 x 512]
    int Kx;             // 32 or 512
};

// One phase: blocks 0..127 = slot0 (Kx=32 layer), 128..255 = slot1 (Kx=512).
// Block (mg=lb>>5, jj=lb&31): 256 batch rows x 16 hidden cols x 4 gates.
// Weights staged to LDS each launch; C fp32 in global; h normal stores
// (kernel boundary provides coherence/ordering -> no flags/fences needed).
__global__ __launch_bounds__(256, 1) void lstm_phase(LA A0, LA A1) {
    __shared__ short8 WldsH[4096];   // Whh slice, 64 KB
    __shared__ short8 WldsI[4096];   // Wih slice, 64 KB (Kx=32 uses 256)

    const int bid = blockIdx.x;
    LA La = (bid < 128) ? A0 : A1;
    if (La.X == nullptr) return;
    const int lb   = bid & 127;
    const int mg   = lb >> 5;
    const int jj   = lb & 31;
    const int m0   = mg * 256;
    const int j0   = jj * 16;
    const int tid  = threadIdx.x;
    const int wid  = tid >> 6;
    const int lane = tid & 63;
    const int quad = lane >> 4;
    const int mrow = m0 + wid * 64 + (lane & 15);

    // stage weight slices (frag-major)
    for (int i = 0; i < 16; ++i) {
        int s = tid + i * 256;
        int frag = s >> 6, ln = s & 63;
        int ks = frag >> 2, g = frag & 3;
        WldsH[s] = *(const short8*)(La.Whh + (size_t)(g * H_ + j0 + (ln & 15)) * H_
                                    + ks * 32 + (ln >> 4) * 8);
    }
    if (La.Kx == 32) {
        if (tid < 256) {
            int frag = tid >> 6, ln = tid & 63;
            int g = frag & 3;   // ks = 0
            WldsI[tid] = *(const short8*)(La.Wih + (size_t)(g * H_ + j0 + (ln & 15)) * F_
                                          + (ln >> 4) * 8);
        }
    } else {
        for (int i = 0; i < 16; ++i) {
            int s = tid + i * 256;
            int frag = s >> 6, ln = s & 63;
            int ks = frag >> 2, g = frag & 3;
            WldsI[s] = *(const short8*)(La.Wih + (size_t)(g * H_ + j0 + (ln & 15)) * H_
                                        + ks * 32 + (ln >> 4) * 8);
        }
    }
    __syncthreads();

    float4v acc[4][4];
    #pragma unroll
    for (int ms = 0; ms < 4; ++ms)
        #pragma unroll
        for (int g = 0; g < 4; ++g)
            acc[ms][g] = (float4v){0.f, 0.f, 0.f, 0.f};

    if (La.Kx == 32) gemm_acc<1, 32>(La.X, WldsI, acc, mrow, quad, lane);
    else             gemm_acc<16, 512>(La.X, WldsI, acc, mrow, quad, lane);
    gemm_acc<16, 512>(La.Hin, WldsH, acc, mrow, quad, lane);

    // epilogue: gates -> c (global fp32), h (bf16)
    const int row16 = lane & 15;
    const int j = j0 + row16;
    const float bi  = La.bias[j];
    const float bff = La.bias[H_ + j];
    const float bg  = La.bias[2 * H_ + j];
    const float bo  = La.bias[3 * H_ + j];
    #pragma unroll
    for (int ms = 0; ms < 4; ++ms) {
        #pragma unroll
        for (int r = 0; r < 4; ++r) {
            int brow = m0 + wid * 64 + ms * 16 + quad * 4 + r;
            float ig = sigmoidf_(acc[ms][0][r] + bi);
            float fg = sigmoidf_(acc[ms][1][r] + bff);
            float gg = tanhf_(acc[ms][2][r] + bg);
            float og = sigmoidf_(acc[ms][3][r] + bo);
            size_t idx = (size_t)brow * H_ + j;
            float cn = fg * La.C[idx] + ig * gg;
            La.C[idx] = cn;
            La.Hout[idx] = __float2bfloat16(og * tanhf_(cn));
        }
    }
}

// ---------------------------------------------------------------------------
// y = h1 @ dec_w^T + dec_b -> Y bf16 [B,32]; optionally store fut fp32
// ---------------------------------------------------------------------------
__global__ __launch_bounds__(256) void dec_kernel(
    const bf16* __restrict__ Hb, const bf16* __restrict__ wb,
    const float* __restrict__ dec_b, bf16* __restrict__ Y,
    float* __restrict__ fut, int step)
{
    int tid = blockIdx.x * 256 + threadIdx.x;  // 32768
    int b = tid >> 5, f = tid & 31;
    const short8* h = (const short8*)(Hb + (size_t)b * H_);
    const short8* w = (const short8*)(wb + (size_t)f * H_);
    float acc = dec_b[f];
    for (int i = 0; i < H_ / 8; ++i) {
        short8 hv = h[i], wv = w[i];
        #pragma unroll
        for (int k = 0; k < 8; ++k)
            acc += b2f_(hv[k]) * b2f_(wv[k]);
    }
    Y[tid] = __float2bfloat16(acc);
    if (step >= 0) fut[(size_t)b * (F_ * NSTEPS_) + f * NSTEPS_ + step] = acc;
}

// ---------------------------------------------------------------------------
__global__ __launch_bounds__(256) void deconv_kernel(
    const float* __restrict__ fut, const float* __restrict__ dw,
    float* __restrict__ out)
{
    int idx = blockIdx.x * 256 + threadIdx.x;
    if (idx >= B_ * 49) return;
    int b = idx / 49, jj = idx % 49;
    int tlo = jj - (KD_ - 1); if (tlo < 0) tlo = 0;
    int thi = jj; if (thi > NSTEPS_ - 1) thi = NSTEPS_ - 1;
    float acc = 0.f;
    for (int f = 0; f < F_; ++f) {
        const float* fr = fut + (size_t)b * (F_ * NSTEPS_) + f * NSTEPS_;
        const float* wr = dw + f * KD_;
        for (int t = tlo; t <= thi; ++t)
            acc += fr[t] * wr[jj - t];
    }
    out[idx] = acc;
}

// ---------------------------------------------------------------------------
extern "C" void kernel_launch(void* const* d_in, const int* in_sizes, int n_in,
                              void* d_out, int out_size, void* d_ws, size_t ws_size,
                              hipStream_t stream) {
    const float* x       = (const float*)d_in[0];
    const float* conv_w  = (const float*)d_in[1];
    const float* conv_b  = (const float*)d_in[2];
    const float* Wih0f   = (const float*)d_in[3];
    const float* Whh0f   = (const float*)d_in[4];
    const float* bih0    = (const float*)d_in[5];
    const float* bhh0    = (const float*)d_in[6];
    const float* Wih1f   = (const float*)d_in[7];
    const float* Whh1f   = (const float*)d_in[8];
    const float* bih1    = (const float*)d_in[9];
    const float* bhh1    = (const float*)d_in[10];
    const float* dec_wf  = (const float*)d_in[11];
    const float* dec_b   = (const float*)d_in[12];
    const float* deconvw = (const float*)d_in[13];
    float* out = (float*)d_out;

    char* ws = (char*)d_ws;
    size_t off = 0;
    auto alloc = [&](size_t bytes) { char* p = ws + off; off = (off + bytes + 255) & ~(size_t)255; return p; };
    bf16*  seq   = (bf16*) alloc((size_t)T_ * B_ * F_ * 2);
    float* b0v   = (float*)alloc(G4H * 4);
    float* b1v   = (float*)alloc(G4H * 4);
    float* c0    = (float*)alloc((size_t)BH * 4);
    float* c1    = (float*)alloc((size_t)BH * 4);
    bf16*  h0    = (bf16*) alloc((size_t)2 * BH * 2);   // 2 slots
    bf16*  h1    = (bf16*) alloc((size_t)2 * BH * 2);
    bf16*  y     = (bf16*) alloc((size_t)B_ * F_ * 2);
    float* fut   = (float*)alloc((size_t)B_ * F_ * NSTEPS_ * 4);
    bf16*  Wih0b = (bf16*) alloc((size_t)G4H * F_ * 2);
    bf16*  Whh0b = (bf16*) alloc((size_t)G4H * H_ * 2);
    bf16*  Wih1b = (bf16*) alloc((size_t)G4H * H_ * 2);
    bf16*  Whh1b = (bf16*) alloc((size_t)G4H * H_ * 2);
    bf16*  dec_wb= (bf16*) alloc((size_t)F_ * H_ * 2);

    hipMemsetAsync(c0, 0, (size_t)BH * 4, stream);
    hipMemsetAsync(c1, 0, (size_t)BH * 4, stream);
    hipMemsetAsync(h0 + BH, 0, (size_t)BH * 2, stream);   // slot 1 = h[-1]
    hipMemsetAsync(h1 + BH, 0, (size_t)BH * 2, stream);

    cvt_kernel<<<(G4H * F_ + 255) / 256, 256, 0, stream>>>(Wih0f, Wih0b, G4H * F_);
    cvt_kernel<<<(G4H * H_ + 255) / 256, 256, 0, stream>>>(Whh0f, Whh0b, G4H * H_);
    cvt_kernel<<<(G4H * H_ + 255) / 256, 256, 0, stream>>>(Wih1f, Wih1b, G4H * H_);
    cvt_kernel<<<(G4H * H_ + 255) / 256, 256, 0, stream>>>(Whh1f, Whh1b, G4H * H_);
    cvt_kernel<<<(F_ * H_ + 255) / 256, 256, 0, stream>>>(dec_wf, dec_wb, F_ * H_);

    bias_kernel<<<16, 256, 0, stream>>>(bih0, bhh0, bih1, bhh1, b0v, b1v);
    conv_kernel<<<B_, 256, 0, stream>>>(x, conv_w, conv_b, seq);

    LA nul; nul.X = nullptr; nul.Wih = nullptr; nul.Whh = nullptr; nul.Hin = nullptr;
    nul.bias = nullptr; nul.C = nullptr; nul.Hout = nullptr; nul.Kx = 0;
    auto mk = [&](const bf16* X, int Kx, const bf16* Wih, const bf16* Whh,
                  const bf16* Hin, const float* bias, float* C, bf16* Hout) {
        LA a; a.X = X; a.Kx = Kx; a.Wih = Wih; a.Whh = Whh;
        a.Hin = Hin; a.bias = bias; a.C = C; a.Hout = Hout; return a;
    };

    // encoder: phases p = 0..150; slot0 does L0(t=p), slot1 does L1(t=p-1)
    for (int p = 0; p <= T_; ++p) {
        LA a0 = nul, a1 = nul;
        if (p < T_)
            a0 = mk(seq + (size_t)p * B_ * F_, F_, Wih0b, Whh0b,
                    h0 + (size_t)((p + 1) & 1) * BH, b0v, c0, h0 + (size_t)(p & 1) * BH);
        if (p >= 1) {
            int t1 = p - 1;
            a1 = mk(h0 + (size_t)(t1 & 1) * BH, H_, Wih1b, Whh1b,
                    h1 + (size_t)((t1 + 1) & 1) * BH, b1v, c1, h1 + (size_t)(t1 & 1) * BH);
        }
        lstm_phase<<<256, 256, 0, stream>>>(a0, a1);
    }

    // decoder: strictly serial y -> L0 -> L1 chain
    dec_kernel<<<128, 256, 0, stream>>>(h1 + (size_t)((T_ - 1) & 1) * BH,
                                        dec_wb, dec_b, y, fut, -1);
    for (int s = 0; s < NSTEPS_; ++s) {
        int t = T_ + s;
        LA a0 = mk(y, F_, Wih0b, Whh0b, h0 + (size_t)((t + 1) & 1) * BH,
                   b0v, c0, h0 + (size_t)(t & 1) * BH);
        lstm_phase<<<256, 256, 0, stream>>>(a0, nul);
        LA a1 = mk(h0 + (size_t)(t & 1) * BH, H_, Wih1b, Whh1b,
                   h1 + (size_t)((t + 1) & 1) * BH, b1v, c1, h1 + (size_t)(t & 1) * BH);
        lstm_phase<<<256, 256, 0, stream>>>(nul, a1);
        dec_kernel<<<128, 256, 0, stream>>>(h1 + (size_t)(t & 1) * BH,
                                            dec_wb, dec_b, y, fut, s);
    }
    deconv_kernel<<<196, 256, 0, stream>>>(fut, deconvw, out);
}